// Round 9
// baseline (146.247 us; speedup 1.0000x reference)
//
#include <hip/hip_runtime.h>
#include <cmath>

// DotMaskLayer: B=16384, D=256, H=64, M=128.
// keep(j) = (j < K) | (128 <= j < 128+K)  [j=256 bias iff K>128; K<=128 in data]
// out[b,h] = tanh( sum_j keep(j)*Y[b,j]*W[b,j,h] ),  W = AUX.reshape(B,257,64)
//
// R9: R7 main kernel + LONGEST-FIRST block scheduling.
// Block time ~ k (U[0,128]); arbitrary dispatch order leaves large-k
// stragglers running at low occupancy during grid drain. Pre-pass bucket-sorts
// b by k descending (129 buckets) into order[] (ws); main kernel processes
// b = order[blockIdx.x]. Within-bucket order is atomic-racy but affects
// scheduling only -- each b is computed entirely by one block, so d_out is
// deterministic. counts/cursor/order are fully rewritten each call.

#define D_DIM 256
#define H_DIM 64
#define ROWS 257
#define ROWSTRIDE (ROWS * H_DIM)   // 16448 floats per batch row of AUX

// ---- ws layout (ints): [0,129) counts, [129,258) cursor, [512, 512+B) order
#define WS_COUNTS 0
#define WS_CURSOR 129
#define WS_ORDER  512

__global__ void count_kernel(const int* __restrict__ K, int* __restrict__ counts, int B)
{
    const int i = blockIdx.x * 256 + threadIdx.x;
    if (i < B) atomicAdd(&counts[K[i]], 1);
}

__global__ void scan_kernel(int* __restrict__ counts, int* __restrict__ cursor)
{
    if (threadIdx.x == 0) {
        int off = 0;
        for (int k = 128; k >= 0; --k) {   // descending: largest k first
            const int c = counts[k];
            cursor[k] = off;
            off += c;
        }
    }
}

__global__ void scatter_kernel(const int* __restrict__ K, int* __restrict__ cursor,
                               int* __restrict__ order, int B)
{
    const int i = blockIdx.x * 256 + threadIdx.x;
    if (i < B) {
        const int p = atomicAdd(&cursor[K[i]], 1);
        order[p] = i;
    }
}

__global__ __launch_bounds__(256, 8)
void dotmask_kernel(const float* __restrict__ X,
                    const float* __restrict__ AUX,
                    const int* __restrict__ K,
                    const int* __restrict__ order,
                    float* __restrict__ out)
{
    const int b    = order[blockIdx.x];
    const int tid  = threadIdx.x;
    const int lane = tid & 63;
    const int w    = tid >> 6;          // wave id 0..3 (all share row b)
    const int jo   = lane >> 4;         // row offset within 4-row chunk
    const int h4   = (lane & 15) * 4;   // this lane's 4 consecutive h's

    const int k = K[b];
    const float* __restrict__ Wb  = AUX + (size_t)b * ROWSTRIDE;
    const float* __restrict__ WbH = Wb + h4;
    const float* __restrict__ Xb  = X   + (size_t)b * D_DIM;

    float ax = 0.f, ay = 0.f, az = 0.f, aw = 0.f;

    // Wave w owns 4-row chunks c = w, w+4, w+8, ... ; 2 chunks per iteration.
    for (int j0 = w * 4; j0 < k; j0 += 32) {
        // ---- chunk A loads ----
        const int ja   = j0 + jo;
        const int ja2  = (ja + 128 > 256) ? 256 : (ja + 128);
        const float4 wa1 = *reinterpret_cast<const float4*>(WbH + ((size_t)ja  << 6));
        const float4 wa2 = *reinterpret_cast<const float4*>(WbH + ((size_t)ja2 << 6));
        const float  xa1r = Xb[ja];
        const float  xa2r = Xb[(ja + 128 > 255) ? 255 : (ja + 128)];

        // ---- chunk B loads (wave-uniform guard: no wasted fetch) ----
        const int j0b = j0 + 16;
        const bool doB = (j0b < k);
        float4 wb1 = make_float4(0,0,0,0), wb2 = make_float4(0,0,0,0);
        float  xb1r = 0.f, xb2r = 0.f;
        int jb = 0;
        if (doB) {
            jb = j0b + jo;
            const int jb2 = (jb + 128 > 256) ? 256 : (jb + 128);
            wb1 = *reinterpret_cast<const float4*>(WbH + ((size_t)jb  << 6));
            wb2 = *reinterpret_cast<const float4*>(WbH + ((size_t)jb2 << 6));
            xb1r = Xb[jb];
            xb2r = Xb[(jb + 128 > 255) ? 255 : (jb + 128)];
        }

        // ---- FMAs (after all loads issued) ----
        const float xa1 = (ja < k) ? xa1r : 0.f;
        const float xa2 = (ja < k) ? xa2r : 0.f;
        ax += xa1 * wa1.x; ay += xa1 * wa1.y; az += xa1 * wa1.z; aw += xa1 * wa1.w;
        ax += xa2 * wa2.x; ay += xa2 * wa2.y; az += xa2 * wa2.z; aw += xa2 * wa2.w;

        const float xb1 = (doB && jb < k) ? xb1r : 0.f;
        const float xb2 = (doB && jb < k) ? xb2r : 0.f;
        ax += xb1 * wb1.x; ay += xb1 * wb1.y; az += xb1 * wb1.z; aw += xb1 * wb1.w;
        ax += xb2 * wb2.x; ay += xb2 * wb2.y; az += xb2 * wb2.z; aw += xb2 * wb2.w;
    }

    // bias row j=256 (kept iff k > 128; never with this data, kept for generality)
    if (k > 128 && w == 0 && jo == 0) {
        const float4 wv = *reinterpret_cast<const float4*>(Wb + (size_t)256 * H_DIM + h4);
        ax += wv.x; ay += wv.y; az += wv.z; aw += wv.w;
    }

    // reduce across the 4 jo-groups (lanes l, l+16, l+32, l+48 share h4)
    ax += __shfl_xor(ax, 16); ay += __shfl_xor(ay, 16);
    az += __shfl_xor(az, 16); aw += __shfl_xor(aw, 16);
    ax += __shfl_xor(ax, 32); ay += __shfl_xor(ay, 32);
    az += __shfl_xor(az, 32); aw += __shfl_xor(aw, 32);

    // combine the 4 waves' partials via LDS
    __shared__ float lds[4][H_DIM];
    if (lane < 16) {
        float4 p; p.x = ax; p.y = ay; p.z = az; p.w = aw;
        *reinterpret_cast<float4*>(&lds[w][h4]) = p;
    }
    __syncthreads();

    if (tid < H_DIM) {
        const float s = lds[0][tid] + lds[1][tid] + lds[2][tid] + lds[3][tid];
        out[(size_t)b * H_DIM + tid] = tanhf(s);
    }
}

extern "C" void kernel_launch(void* const* d_in, const int* in_sizes, int n_in,
                              void* d_out, int out_size, void* d_ws, size_t ws_size,
                              hipStream_t stream)
{
    const float* X   = (const float*)d_in[0];
    const float* AUX = (const float*)d_in[1];
    const int*   K   = (const int*)d_in[2];
    float* out = (float*)d_out;
    int*   wsi = (int*)d_ws;

    const int B = in_sizes[2];                 // 16384
    const int nb = (B + 255) / 256;            // 64 blocks for the tiny passes

    // zero bucket counts (cursor/order are fully overwritten downstream)
    hipMemsetAsync(wsi + WS_COUNTS, 0, 129 * sizeof(int), stream);

    count_kernel  <<<nb, 256, 0, stream>>>(K, wsi + WS_COUNTS, B);
    scan_kernel   <<<1, 64, 0, stream>>>(wsi + WS_COUNTS, wsi + WS_CURSOR);
    scatter_kernel<<<nb, 256, 0, stream>>>(K, wsi + WS_CURSOR, wsi + WS_ORDER, B);

    dotmask_kernel<<<B, 256, 0, stream>>>(X, AUX, K, wsi + WS_ORDER, out);
}

// Round 10
// 122.031 us; speedup vs baseline: 1.1984x; 1.1984x over previous
//
#include <hip/hip_runtime.h>
#include <cmath>

// DotMaskLayer: B=16384, D=256, H=64, M=128.
// keep(j) = (j < K) | (128 <= j < 128+K)  [j=256 bias iff K>128; K<=128 in data]
// out[b,h] = tanh( sum_j keep(j)*Y[b,j]*W[b,j,h] ),  W = AUX.reshape(B,257,64)
//
// R10: DRAIN-TAIL FIX WITHOUT SORTING. Every b is split into S=4 sub-blocks
// (blockIdx = 4b+s, adjacent -> co-scheduled -> locality preserved). Each
// sub-block computes a contiguous quarter of b's chunk list and writes a
// partial 64-vector to its own ws slot (deterministic, no atomics); finalize
// kernel sums 4 slots + tanh. Max block duration drops 16->~4us and grid
// slack rises 8->32 rounds, shrinking the end-of-grid straggler cost ~4x.
// Total fetch and wave-slot quantization are unchanged vs R7.

#define D_DIM 256
#define H_DIM 64
#define ROWS 257
#define ROWSTRIDE (ROWS * H_DIM)   // 16448 floats per batch row of AUX
#define NSPLIT 4

__global__ __launch_bounds__(256, 8)
void dotmask_part(const float* __restrict__ X,
                  const float* __restrict__ AUX,
                  const int* __restrict__ K,
                  float* __restrict__ part,   // [NSPLIT][B][64]
                  int B)
{
    const int bid  = blockIdx.x;
    const int b    = bid >> 2;          // batch row
    const int s    = bid & 3;           // split id 0..3
    const int tid  = threadIdx.x;
    const int lane = tid & 63;
    const int w    = tid >> 6;          // wave id 0..3
    const int jo   = lane >> 4;         // row offset within 4-row chunk
    const int h4   = (lane & 15) * 4;   // this lane's 4 consecutive h's

    const int k = K[b];
    const float* __restrict__ Wb  = AUX + (size_t)b * ROWSTRIDE;
    const float* __restrict__ WbH = Wb + h4;
    const float* __restrict__ Xb  = X   + (size_t)b * D_DIM;

    // chunk-pair list: c = 0..C-1, chunk c = rows [4c,4c+4) + mirror (+128).
    // split s owns contiguous [lo, hi).
    const int C  = (k + 3) >> 2;
    const int lo = (C * s) >> 2;
    const int hi = (C * (s + 1)) >> 2;

    float ax = 0.f, ay = 0.f, az = 0.f, aw = 0.f;

    // wave w takes chunks lo+w, lo+w+4, ... (round-robin within the split)
    for (int c = lo + w; c < hi; c += 4) {
        const int j   = 4 * c + jo;               // <= 4C-1 <= k+2 <= 130
        const int j2  = j + 128;                  // <= 258
        const int j2c = (j2 > 256) ? 256 : j2;    // clamped lanes mask-zeroed

        const float4 w1 = *reinterpret_cast<const float4*>(WbH + ((size_t)j   << 6));
        const float4 w2 = *reinterpret_cast<const float4*>(WbH + ((size_t)j2c << 6));
        const float  x1r = Xb[j];
        const float  x2r = Xb[(j2 > 255) ? 255 : j2];

        const bool  m  = (j < k);
        const float x1 = m ? x1r : 0.f;
        const float x2 = m ? x2r : 0.f;

        ax += x1 * w1.x; ay += x1 * w1.y; az += x1 * w1.z; aw += x1 * w1.w;
        ax += x2 * w2.x; ay += x2 * w2.y; az += x2 * w2.z; aw += x2 * w2.w;
    }

    // bias row j=256 (kept iff k > 128; never with this data, kept for generality)
    if (k > 128 && s == 0 && w == 0 && jo == 0) {
        const float4 wv = *reinterpret_cast<const float4*>(Wb + (size_t)256 * H_DIM + h4);
        ax += wv.x; ay += wv.y; az += wv.z; aw += wv.w;
    }

    // reduce across the 4 jo-groups (lanes l, l+16, l+32, l+48 share h4)
    ax += __shfl_xor(ax, 16); ay += __shfl_xor(ay, 16);
    az += __shfl_xor(az, 16); aw += __shfl_xor(aw, 16);
    ax += __shfl_xor(ax, 32); ay += __shfl_xor(ay, 32);
    az += __shfl_xor(az, 32); aw += __shfl_xor(aw, 32);

    // combine the 4 waves' partials via LDS, then write this split's slot
    __shared__ float lds[4][H_DIM];
    if (lane < 16) {
        float4 p; p.x = ax; p.y = ay; p.z = az; p.w = aw;
        *reinterpret_cast<float4*>(&lds[w][h4]) = p;
    }
    __syncthreads();

    if (tid < H_DIM) {
        const float v = lds[0][tid] + lds[1][tid] + lds[2][tid] + lds[3][tid];
        part[((size_t)s * B + b) * H_DIM + tid] = v;   // always written (zeros ok)
    }
}

__global__ __launch_bounds__(256)
void finalize_kernel(const float* __restrict__ part,
                     float* __restrict__ out, int n)   // n = B*64, float4-granular
{
    const int i = blockIdx.x * 256 + threadIdx.x;      // over n/4
    if (i * 4 >= n) return;
    const float4 p0 = *reinterpret_cast<const float4*>(part + 0 * (size_t)n + 4 * (size_t)i);
    const float4 p1 = *reinterpret_cast<const float4*>(part + 1 * (size_t)n + 4 * (size_t)i);
    const float4 p2 = *reinterpret_cast<const float4*>(part + 2 * (size_t)n + 4 * (size_t)i);
    const float4 p3 = *reinterpret_cast<const float4*>(part + 3 * (size_t)n + 4 * (size_t)i);
    float4 r;
    r.x = tanhf(p0.x + p1.x + p2.x + p3.x);
    r.y = tanhf(p0.y + p1.y + p2.y + p3.y);
    r.z = tanhf(p0.z + p1.z + p2.z + p3.z);
    r.w = tanhf(p0.w + p1.w + p2.w + p3.w);
    *reinterpret_cast<float4*>(out + 4 * (size_t)i) = r;
}

extern "C" void kernel_launch(void* const* d_in, const int* in_sizes, int n_in,
                              void* d_out, int out_size, void* d_ws, size_t ws_size,
                              hipStream_t stream)
{
    const float* X   = (const float*)d_in[0];
    const float* AUX = (const float*)d_in[1];
    const int*   K   = (const int*)d_in[2];
    float* out  = (float*)d_out;
    float* part = (float*)d_ws;                // NSPLIT * B * 64 floats = 16 MB

    const int B = in_sizes[2];                 // 16384
    const int n = B * H_DIM;

    dotmask_part<<<B * NSPLIT, 256, 0, stream>>>(X, AUX, K, part, B);
    finalize_kernel<<<(n / 4 + 255) / 256, 256, 0, stream>>>(part, out, n);
}

// Round 11
// 113.110 us; speedup vs baseline: 1.2930x; 1.0789x over previous
//
#include <hip/hip_runtime.h>
#include <cmath>

// DotMaskLayer: B=16384, D=256, H=64, M=128.
// keep(j) = (j < K) | (128 <= j < 128+K)  [j=256 bias iff K>128; K<=128 in data]
// out[b,h] = tanh( sum_j keep(j)*Y[b,j]*W[b,j,h] ),  W = AUX.reshape(B,257,64)
//
// R11: R7 with CONTIGUOUS PER-WAVE SEGMENTS (isolates request-order).
// R7 gave each wave chunks w, w+4, w+8 (1KB requests at 4KB stride). Here
// wave w owns the contiguous chunk range [C*w/4, C*(w+1)/4), walked
// sequentially with the same 2-chunk unroll -> each wave's request stream is
// address-sequential (DRAM page-hit friendly). Same bytes, same +-1 chunk
// quantization, no extra kernels. Tests the last live theory for the
// 114us-vs-90us gap (ILP/lockstep/drain/sort all null or refuted).

#define D_DIM 256
#define H_DIM 64
#define ROWS 257
#define ROWSTRIDE (ROWS * H_DIM)   // 16448 floats per batch row of AUX

__global__ __launch_bounds__(256, 8)
void dotmask_kernel(const float* __restrict__ X,
                    const float* __restrict__ AUX,
                    const int* __restrict__ K,
                    float* __restrict__ out)
{
    const int b    = blockIdx.x;
    const int tid  = threadIdx.x;
    const int lane = tid & 63;
    const int w    = tid >> 6;          // wave id 0..3 (all share row b)
    const int jo   = lane >> 4;         // row offset within 4-row chunk
    const int h4   = (lane & 15) * 4;   // this lane's 4 consecutive h's

    const int k = K[b];
    const float* __restrict__ Wb  = AUX + (size_t)b * ROWSTRIDE;
    const float* __restrict__ WbH = Wb + h4;
    const float* __restrict__ Xb  = X   + (size_t)b * D_DIM;

    float ax = 0.f, ay = 0.f, az = 0.f, aw = 0.f;

    // chunk c covers rows [4c,4c+4) + mirror (+128). Wave w owns the
    // contiguous range [lo, hi), hi-lo uniform +-1 across waves.
    const int C  = (k + 3) >> 2;
    const int lo = (C * w) >> 2;
    const int hi = (C * (w + 1)) >> 2;

    for (int c = lo; c < hi; c += 2) {
        // ---- chunk A loads ----
        const int ja   = 4 * c + jo;               // <= 4C-1+3 <= k+6 <= 134
        const int ja2  = (ja + 128 > 256) ? 256 : (ja + 128);
        const float4 wa1 = *reinterpret_cast<const float4*>(WbH + ((size_t)ja  << 6));
        const float4 wa2 = *reinterpret_cast<const float4*>(WbH + ((size_t)ja2 << 6));
        const float  xa1r = Xb[ja];
        const float  xa2r = Xb[(ja + 128 > 255) ? 255 : (ja + 128)];

        // ---- chunk B loads (wave-uniform guard: no wasted fetch) ----
        const bool doB = (c + 1 < hi);
        float4 wb1 = make_float4(0,0,0,0), wb2 = make_float4(0,0,0,0);
        float  xb1r = 0.f, xb2r = 0.f;
        int jb = 0;
        if (doB) {
            jb = 4 * (c + 1) + jo;
            const int jb2 = (jb + 128 > 256) ? 256 : (jb + 128);
            wb1 = *reinterpret_cast<const float4*>(WbH + ((size_t)jb  << 6));
            wb2 = *reinterpret_cast<const float4*>(WbH + ((size_t)jb2 << 6));
            xb1r = Xb[jb];
            xb2r = Xb[(jb + 128 > 255) ? 255 : (jb + 128)];
        }

        // ---- FMAs (after all loads issued) ----
        const float xa1 = (ja < k) ? xa1r : 0.f;
        const float xa2 = (ja < k) ? xa2r : 0.f;
        ax += xa1 * wa1.x; ay += xa1 * wa1.y; az += xa1 * wa1.z; aw += xa1 * wa1.w;
        ax += xa2 * wa2.x; ay += xa2 * wa2.y; az += xa2 * wa2.z; aw += xa2 * wa2.w;

        const float xb1 = (doB && jb < k) ? xb1r : 0.f;
        const float xb2 = (doB && jb < k) ? xb2r : 0.f;
        ax += xb1 * wb1.x; ay += xb1 * wb1.y; az += xb1 * wb1.z; aw += xb1 * wb1.w;
        ax += xb2 * wb2.x; ay += xb2 * wb2.y; az += xb2 * wb2.z; aw += xb2 * wb2.w;
    }

    // bias row j=256 (kept iff k > 128; never with this data, kept for generality)
    if (k > 128 && w == 0 && jo == 0) {
        const float4 wv = *reinterpret_cast<const float4*>(Wb + (size_t)256 * H_DIM + h4);
        ax += wv.x; ay += wv.y; az += wv.z; aw += wv.w;
    }

    // reduce across the 4 jo-groups (lanes l, l+16, l+32, l+48 share h4)
    ax += __shfl_xor(ax, 16); ay += __shfl_xor(ay, 16);
    az += __shfl_xor(az, 16); aw += __shfl_xor(aw, 16);
    ax += __shfl_xor(ax, 32); ay += __shfl_xor(ay, 32);
    az += __shfl_xor(az, 32); aw += __shfl_xor(aw, 32);

    // combine the 4 waves' partials via LDS
    __shared__ float lds[4][H_DIM];
    if (lane < 16) {
        float4 p; p.x = ax; p.y = ay; p.z = az; p.w = aw;
        *reinterpret_cast<float4*>(&lds[w][h4]) = p;
    }
    __syncthreads();

    if (tid < H_DIM) {
        const float s = lds[0][tid] + lds[1][tid] + lds[2][tid] + lds[3][tid];
        out[(size_t)b * H_DIM + tid] = tanhf(s);
    }
}

extern "C" void kernel_launch(void* const* d_in, const int* in_sizes, int n_in,
                              void* d_out, int out_size, void* d_ws, size_t ws_size,
                              hipStream_t stream)
{
    const float* X   = (const float*)d_in[0];
    const float* AUX = (const float*)d_in[1];
    const int*   K   = (const int*)d_in[2];
    float* out = (float*)d_out;

    const int B = in_sizes[2];                 // 16384
    dotmask_kernel<<<B, 256, 0, stream>>>(X, AUX, K, out);
}